// Round 9
// baseline (378.735 us; speedup 1.0000x reference)
//
#include <hip/hip_runtime.h>
#include <hip/hip_bf16.h>
#include <math.h>

// ---------------------------------------------------------------------------
// FaceAttnProcessor forward. R8: split-K replaced by 64x64-tile GEMM (384
// blocks, no partials) for all N=768 GEMMs; GEGLU fused into ff1 epilogue
// via interleaved w1 layout + shfl_xor pairing. Attention = R7 key-split
// static-max MFMA flash. B=2, N=1024, C=768, H=12, d=64, INNER=3072.
// ---------------------------------------------------------------------------

#define C_DIM 768
#define B_DIM 2
#define N_DIM 1024
#define NC_DIM 1040
#define L_DIM 93
#define TEXT_LEN 77
#define INNER 3072
#define MNX 1572864   // 2048*768

typedef unsigned short ushort_t;
typedef __bf16 bf16x8 __attribute__((ext_vector_type(8)));
typedef float f32x4 __attribute__((ext_vector_type(4)));

__device__ __forceinline__ ushort_t f2b(float f) {
  __hip_bfloat16 h = __float2bfloat16(f);
  return *(ushort_t*)&h;
}
__device__ __forceinline__ float b2f(ushort_t u) {
  __hip_bfloat16 h = *(__hip_bfloat16*)&u;
  return __bfloat162float(h);
}

__device__ __forceinline__ void g2lds16(const void* g, void* l) {
  __builtin_amdgcn_global_load_lds(
      (const __attribute__((address_space(1))) unsigned int*)g,
      (__attribute__((address_space(3))) unsigned int*)l, 16, 0, 0);
}

// ---------------- workspace map (byte offsets) ----------------------------
#define WX1    0u           // fp32 x1 (2048*768)
#define WX2    6291456u     // fp32 x2
#define WQKV   12582912u    // u16 qkv_b [2080][2304]; later q2b/kv2b
#define WBB1   22167552u    // comb_b (phase A) / opart[4] fp32 (phase B)
#define WG     47333376u    // lbuf (384KB) + attn_b (WG+512KB) / g_b (phase C)
#define WS1    59916288u    // u16 hh / x2b [2048][768]
#define WTEXT  63062016u    // u16 text_b [154][768]
#define WATT2  63298560u    // u16 attn2b [2048][768]
#define WWQKV  66444288u    // u16 wqkv_t [2304][768]
#define WWO    69983232u    // u16 wo_t   [768][768]
#define WW1    71162880u    // u16 w1_t   [6144][768] (interleaved a/gate rows)
#define WW2    80600064u    // u16 w2_t   [768][3072]
#define WCAWQ  85318656u    // u16 cawq_t [768][768]
#define WCAKV  86498304u    // u16 cakv_t [1536][768]
#define WCAWO  88857600u    // u16 cawo_t [768][768]
#define WVT1   90037248u    // u16 Vt self  [2][12][64][1088]
#define WVT2   93379584u    // u16 Vt cross [2][12][64][128]
#define WOPART WBB1                 // fp32 opart[4][2048][768] = 25,165,824
#define WLBUF  WG                   // fp32 lbuf[4][2048][12]
#define WATTN  (WG + 524288u)       // u16 attn_b (dead before g_b written)
// end: 93,772,800 B

// ---------------- block reduction (256 threads = 4 waves) -----------------
__device__ __forceinline__ float block_sum(float v, float* sh) {
#pragma unroll
  for (int o = 32; o > 0; o >>= 1) v += __shfl_down(v, o);
  int lane = threadIdx.x & 63, w = threadIdx.x >> 6;
  if (lane == 0) sh[w] = v;
  __syncthreads();
  float r = sh[0] + sh[1] + sh[2] + sh[3];
  __syncthreads();
  return r;
}

// ---------------- batched weight cast+transpose ---------------------------
// fp32 [K][N] -> bf16 [N][K]; ileave=1 (ff_w1): dst row = 2c (col c<3072)
// or 2(c-3072)+1 (gate cols) so a/gate pairs are adjacent rows.
struct WtDesc {
  const float* src[10];
  ushort_t*    dst[10];
  int K[10];
  int N[10];
  int tilesX[10];
  int ileave[10];
  int start[11];
};

__global__ __launch_bounds__(256)
void wtrans_batched(WtDesc d) {
  __shared__ float tile[64][65];
  int bid = blockIdx.x;
  int j = 0;
  while (j < 9 && bid >= d.start[j + 1]) ++j;
  int ti = bid - d.start[j];
  int K = d.K[j], N = d.N[j];
  int n0 = (ti % d.tilesX[j]) * 64, k0 = (ti / d.tilesX[j]) * 64;
  const float* in = d.src[j];
  ushort_t* out = d.dst[j];
  int il = d.ileave[j];
  int t = threadIdx.x;
#pragma unroll
  for (int p = 0; p < 16; ++p) {
    int idx = t + p * 256;
    int r = idx >> 6, c = idx & 63;
    tile[r][c] = in[(size_t)(k0 + r) * N + n0 + c];
  }
  __syncthreads();
#pragma unroll
  for (int p = 0; p < 16; ++p) {
    int idx = t + p * 256;
    int r = idx >> 6, c = idx & 63;
    int nrow = n0 + r;
    int dstrow = il ? ((nrow < INNER) ? (nrow * 2) : ((nrow - INNER) * 2 + 1)) : nrow;
    out[(size_t)dstrow * K + k0 + c] = f2b(tile[c][r]);
  }
}

// ---------------- LN(x) and LN(face) -> comb (bf16) -----------------------
__global__ __launch_bounds__(256)
void ln_concat_kernel(const float* __restrict__ x, const float* __restrict__ enc,
                      const float* __restrict__ g, const float* __restrict__ b,
                      ushort_t* __restrict__ comb) {
  __shared__ float sh[4];
  int r = blockIdx.x;
  int bb = r / NC_DIM, i = r % NC_DIM;
  const float* src = (i < N_DIM)
      ? (x   + ((size_t)bb * N_DIM + i) * C_DIM)
      : (enc + ((size_t)bb * L_DIM + TEXT_LEN + (i - N_DIM)) * C_DIM);
  float v[3];
#pragma unroll
  for (int j = 0; j < 3; ++j) v[j] = src[threadIdx.x + j * 256];
  float mean = block_sum(v[0] + v[1] + v[2], sh) * (1.f / C_DIM);
  float sq = 0.f;
#pragma unroll
  for (int j = 0; j < 3; ++j) { float d = v[j] - mean; sq += d * d; }
  float rstd = rsqrtf(block_sum(sq, sh) * (1.f / C_DIM) + 1e-5f);
  ushort_t* dst = comb + (size_t)r * C_DIM;
#pragma unroll
  for (int j = 0; j < 3; ++j) {
    int c = threadIdx.x + j * 256;
    dst[c] = f2b((v[j] - mean) * rstd * g[c] + b[c]);
  }
}

// ---------------- double layernorm: fp32 in -> bf16 out -------------------
__global__ __launch_bounds__(256)
void ln_double_kernel(const float* __restrict__ src,
                      const float* __restrict__ g1, const float* __restrict__ b1,
                      const float* __restrict__ g2, const float* __restrict__ b2,
                      ushort_t* __restrict__ out) {
  __shared__ float sh[4];
  const float* s = src + (size_t)blockIdx.x * C_DIM;
  float v[3];
#pragma unroll
  for (int j = 0; j < 3; ++j) v[j] = s[threadIdx.x + j * 256];
  float mean = block_sum(v[0] + v[1] + v[2], sh) * (1.f / C_DIM);
  float sq = 0.f;
#pragma unroll
  for (int j = 0; j < 3; ++j) { float d = v[j] - mean; sq += d * d; }
  float rstd = rsqrtf(block_sum(sq, sh) * (1.f / C_DIM) + 1e-5f);
  float y[3];
#pragma unroll
  for (int j = 0; j < 3; ++j) {
    int c = threadIdx.x + j * 256;
    y[j] = (v[j] - mean) * rstd * g1[c] + b1[c];
  }
  float mean2 = block_sum(y[0] + y[1] + y[2], sh) * (1.f / C_DIM);
  sq = 0.f;
#pragma unroll
  for (int j = 0; j < 3; ++j) { float d = y[j] - mean2; sq += d * d; }
  float rstd2 = rsqrtf(block_sum(sq, sh) * (1.f / C_DIM) + 1e-5f);
  ushort_t* dst = out + (size_t)blockIdx.x * C_DIM;
#pragma unroll
  for (int j = 0; j < 3; ++j) {
    int c = threadIdx.x + j * 256;
    dst[c] = f2b((y[j] - mean2) * rstd2 * g2[c] + b2[c]);
  }
}

// ---------------- bf16 MFMA GEMM, 128x128 tile, double-buffered ------------
// Og != null: GEGLU epilogue — w1 rows interleaved (even=a, odd=gate);
// pair exchanged via shfl_xor(1); even lanes write a*gelu(gate) to
// Og[row][col>>1] (width INNER). Else: bias/res/alpha epilogue.
__global__ __launch_bounds__(256)
void gemm_bf16(const ushort_t* __restrict__ A, const ushort_t* __restrict__ Bt,
               float* __restrict__ Out, ushort_t* __restrict__ Ob,
               ushort_t* __restrict__ Og,
               int M, int N, int K,
               const float* __restrict__ bias, const float* __restrict__ res,
               const float* __restrict__ alphaPtr) {
  __shared__ ushort_t sA[2][128 * 32];
  __shared__ ushort_t sB[2][128 * 32];
  int t = threadIdx.x;
  int w = t >> 6, ln = t & 63;
  int m0 = blockIdx.y * 128, n0 = blockIdx.x * 128;
  int wm = (w >> 1) * 64, wn = (w & 1) * 64;
  int lr = ln & 15, lq = ln >> 4;
  int seg_r = ln >> 2, seg_c = (ln & 3) * 8;

  f32x4 acc[4][4];
#pragma unroll
  for (int mi = 0; mi < 4; ++mi)
#pragma unroll
    for (int ni = 0; ni < 4; ++ni) acc[mi][ni] = (f32x4){0.f, 0.f, 0.f, 0.f};

#define STAGE(k0_, buf_)                                                     \
  do {                                                                       \
    _Pragma("unroll") for (int l = 0; l < 2; ++l) {                          \
      int s = w * 2 + l;                                                     \
      int arow = m0 + s * 16 + seg_r;                                        \
      arow = arow < M ? arow : M - 1;                                        \
      g2lds16(A + (size_t)arow * K + (k0_) + seg_c, &sA[buf_][s * 512]);     \
      int nrow = n0 + s * 16 + seg_r;                                        \
      g2lds16(Bt + (size_t)nrow * K + (k0_) + seg_c, &sB[buf_][s * 512]);    \
    }                                                                        \
  } while (0)

  STAGE(0, 0);
  __syncthreads();
  int cur = 0;
  for (int k0 = 0; k0 < K; k0 += 32) {
    if (k0 + 32 < K) STAGE(k0 + 32, cur ^ 1);
    bf16x8 af[4], bfr[4];
#pragma unroll
    for (int mi = 0; mi < 4; ++mi)
      af[mi] = *(const bf16x8*)&sA[cur][(wm + mi * 16 + lr) * 32 + lq * 8];
#pragma unroll
    for (int ni = 0; ni < 4; ++ni)
      bfr[ni] = *(const bf16x8*)&sB[cur][(wn + ni * 16 + lr) * 32 + lq * 8];
#pragma unroll
    for (int mi = 0; mi < 4; ++mi)
#pragma unroll
      for (int ni = 0; ni < 4; ++ni)
        acc[mi][ni] = __builtin_amdgcn_mfma_f32_16x16x32_bf16(
            af[mi], bfr[ni], acc[mi][ni], 0, 0, 0);
    __syncthreads();
    cur ^= 1;
  }
#undef STAGE

  if (Og) {
    // GEGLU epilogue: even permuted col = a_c, odd = gate_c, c = col>>1
#pragma unroll
    for (int mi = 0; mi < 4; ++mi)
#pragma unroll
      for (int ni = 0; ni < 4; ++ni) {
        int col = n0 + wn + ni * 16 + lr;
#pragma unroll
        for (int r = 0; r < 4; ++r) {
          float val = acc[mi][ni][r];
          float other = __shfl_xor(val, 1);   // uniform: all lanes shuffle
          if (!(lr & 1)) {
            float a = val, gate = other;
            float ge = 0.5f * gate * (1.f + erff(gate * 0.70710678118654752f));
            int row = m0 + wm + mi * 16 + lq * 4 + r;
            Og[(size_t)row * INNER + (col >> 1)] = f2b(a * ge);
          }
        }
      }
  } else {
    float f = alphaPtr ? tanhf(alphaPtr[0]) : 1.0f;
#pragma unroll
    for (int mi = 0; mi < 4; ++mi)
#pragma unroll
      for (int ni = 0; ni < 4; ++ni) {
        int col = n0 + wn + ni * 16 + lr;
        float bv = bias ? bias[col] : 0.f;
#pragma unroll
        for (int r = 0; r < 4; ++r) {
          int row = m0 + wm + mi * 16 + lq * 4 + r;
          if (row < M) {
            float val = acc[mi][ni][r] + bv;
            if (res) val = res[(size_t)row * N + col] + f * val;
            if (Out) Out[(size_t)row * N + col] = val;
            if (Ob)  Ob[(size_t)row * N + col] = f2b(val);
          }
        }
      }
  }
}

// ---------------- bf16 MFMA GEMM, 64x64 tile (for skinny N=768) ------------
// 4 waves, each one 32x32 subtile (2x2 MFMA 16x16x32). 384 blocks at
// N=768/M=2048 — no split-K, fused epilogue. BK=32 double-buffered.
__global__ __launch_bounds__(256)
void gemm64(const ushort_t* __restrict__ A, const ushort_t* __restrict__ Bt,
            float* __restrict__ Out, ushort_t* __restrict__ Ob,
            int M, int N, int K,
            const float* __restrict__ bias, const float* __restrict__ res,
            const float* __restrict__ alphaPtr) {
  __shared__ ushort_t sA[2][64 * 32];
  __shared__ ushort_t sB[2][64 * 32];
  int t = threadIdx.x;
  int w = t >> 6, ln = t & 63;
  int m0 = blockIdx.y * 64, n0 = blockIdx.x * 64;
  int wm = (w >> 1) * 32, wn = (w & 1) * 32;
  int lr = ln & 15, lq = ln >> 4;
  int seg_r = ln >> 2, seg_c = (ln & 3) * 8;

  f32x4 acc[2][2];
#pragma unroll
  for (int mi = 0; mi < 2; ++mi)
#pragma unroll
    for (int ni = 0; ni < 2; ++ni) acc[mi][ni] = (f32x4){0.f, 0.f, 0.f, 0.f};

#define STAGE64(k0_, buf_)                                                   \
  do {                                                                       \
    int arow = m0 + w * 16 + seg_r;                                          \
    arow = arow < M ? arow : M - 1;                                          \
    g2lds16(A + (size_t)arow * K + (k0_) + seg_c, &sA[buf_][w * 512]);       \
    int nrow = n0 + w * 16 + seg_r;                                          \
    g2lds16(Bt + (size_t)nrow * K + (k0_) + seg_c, &sB[buf_][w * 512]);      \
  } while (0)

  STAGE64(0, 0);
  __syncthreads();
  int cur = 0;
  for (int k0 = 0; k0 < K; k0 += 32) {
    if (k0 + 32 < K) STAGE64(k0 + 32, cur ^ 1);
    bf16x8 af[2], bfr[2];
#pragma unroll
    for (int mi = 0; mi < 2; ++mi)
      af[mi] = *(const bf16x8*)&sA[cur][(wm + mi * 16 + lr) * 32 + lq * 8];
#pragma unroll
    for (int ni = 0; ni < 2; ++ni)
      bfr[ni] = *(const bf16x8*)&sB[cur][(wn + ni * 16 + lr) * 32 + lq * 8];
#pragma unroll
    for (int mi = 0; mi < 2; ++mi)
#pragma unroll
      for (int ni = 0; ni < 2; ++ni)
        acc[mi][ni] = __builtin_amdgcn_mfma_f32_16x16x32_bf16(
            af[mi], bfr[ni], acc[mi][ni], 0, 0, 0);
    __syncthreads();
    cur ^= 1;
  }
#undef STAGE64

  float f = alphaPtr ? tanhf(alphaPtr[0]) : 1.0f;
#pragma unroll
  for (int mi = 0; mi < 2; ++mi)
#pragma unroll
    for (int ni = 0; ni < 2; ++ni) {
      int col = n0 + wn + ni * 16 + lr;
      float bv = bias ? bias[col] : 0.f;
#pragma unroll
      for (int r = 0; r < 4; ++r) {
        int row = m0 + wm + mi * 16 + lq * 4 + r;
        if (row < M) {
          float val = acc[mi][ni][r] + bv;
          if (res) val = res[(size_t)row * N + col] + f * val;
          if (Out) Out[(size_t)row * N + col] = val;
          if (Ob)  Ob[(size_t)row * N + col] = f2b(val);
        }
      }
    }
}

// ---------------- V transpose: strided bf16 [key][64] -> Vt [dv][Nkp] -----
__global__ __launch_bounds__(256)
void vtrans_kernel(const ushort_t* __restrict__ V, ushort_t* __restrict__ Vt,
                   int rows_per_b, int stride, int Nk, int Nkp) {
  __shared__ ushort_t tile[64][68];
  int k0 = blockIdx.x * 64;
  int h = blockIdx.y, b = blockIdx.z;
  int t = threadIdx.x;
#pragma unroll
  for (int p = 0; p < 4; ++p) {
    int r = p * 16 + (t >> 4), c = (t & 15) * 4;
    int key = k0 + r;
    ushort4 u = make_ushort4(0, 0, 0, 0);
    if (key < Nk)
      u = *(const ushort4*)&V[((size_t)(b * rows_per_b + key)) * stride + h * 64 + c];
    *(ushort4*)&tile[r][c] = u;
  }
  __syncthreads();
  size_t base = ((size_t)(b * 12 + h)) * 64 * Nkp;
#pragma unroll
  for (int p = 0; p < 4; ++p) {
    int dv = p * 16 + (t >> 4), kc = (t & 15) * 4;
    ushort4 u;
    u.x = tile[kc + 0][dv]; u.y = tile[kc + 1][dv];
    u.z = tile[kc + 2][dv]; u.w = tile[kc + 3][dv];
    *(ushort4*)&Vt[base + (size_t)dv * Nkp + k0 + kc] = u;
  }
}

// ---------------- MFMA flash attention (key-split + static-max) -----------
__global__ __launch_bounds__(256)
void attn_mfma(const ushort_t* __restrict__ Q, const ushort_t* __restrict__ K,
               const ushort_t* __restrict__ Vt, ushort_t* __restrict__ O,
               float* __restrict__ Opart, float* __restrict__ lbuf,
               int q_rows_per_b, int kv_rows_per_b, int Nk, int Nkp,
               int qstride, int kstride, int nchunk) {
  __shared__ ushort_t sQ[4096];
  __shared__ ushort_t sK[2][4096];
  __shared__ ushort_t sV[2][4096];
  __shared__ ushort_t sP[4][1024];
  const float scale = 0.18033688011112042f;   // 1/8 * log2(e)
  const float M0 = 16.0f;
  int t = threadIdx.x;
  int w = t >> 6, ln = t & 63;
  int col = ln & 15, quad = ln >> 4;
  int z = blockIdx.z;
  int b = z / nchunk, kc = z % nchunk;
  int h = blockIdx.y, q0 = blockIdx.x * 64;
  size_t vt_base = ((size_t)(b * 12 + h)) * 64 * Nkp;
  int ntiles = Nkp >> 6;
  int t0 = (kc * ntiles) / nchunk;
  int t1 = ((kc + 1) * ntiles) / nchunk;

#define STAGE_KV(kt_, bb_)                                                    \
  do {                                                                        \
    _Pragma("unroll") for (int s = 0; s < 2; ++s) {                           \
      int key = (kt_) * 64 + w * 16 + (ln >> 2);                              \
      g2lds16(K + (size_t)(b * kv_rows_per_b + key) * kstride                 \
                + h * 64 + s * 32 + (ln & 3) * 8,                             \
              (char*)sK[bb_] + s * 4096 + w * 1024);                          \
      int dv = w * 16 + (ln >> 2);                                            \
      g2lds16(Vt + vt_base + (size_t)dv * Nkp                                 \
                + (kt_) * 64 + s * 32 + (ln & 3) * 8,                         \
              (char*)sV[bb_] + s * 4096 + w * 1024);                          \
    }                                                                         \
  } while (0)

#pragma unroll
  for (int s = 0; s < 2; ++s) {
    int r = q0 + w * 16 + (ln >> 2);
    g2lds16(Q + (size_t)(b * q_rows_per_b + r) * qstride + h * 64 + s * 32 + (ln & 3) * 8,
            (char*)sQ + s * 4096 + w * 1024);
  }
  STAGE_KV(t0, 0);
  __syncthreads();
  bf16x8 qa[2];
#pragma unroll
  for (int s = 0; s < 2; ++s)
    qa[s] = *(const bf16x8*)&sQ[s * 2048 + (w * 16 + col) * 32 + quad * 8];

  f32x4 oacc[4];
#pragma unroll
  for (int i = 0; i < 4; ++i) oacc[i] = (f32x4){0.f, 0.f, 0.f, 0.f};
  float l_i[4] = {0.f, 0.f, 0.f, 0.f};

  ushort_t* sPw = sP[w];
  int bb = 0;

  for (int kt = t0; kt < t1; ++kt) {
    if (kt + 1 < t1) STAGE_KV(kt + 1, bb ^ 1);

    f32x4 cs[4];
#pragma unroll
    for (int nblk = 0; nblk < 4; ++nblk) {
      cs[nblk] = (f32x4){0.f, 0.f, 0.f, 0.f};
#pragma unroll
      for (int s = 0; s < 2; ++s) {
        bf16x8 kb = *(const bf16x8*)&sK[bb][s * 2048 + (nblk * 16 + col) * 32 + quad * 8];
        cs[nblk] = __builtin_amdgcn_mfma_f32_16x16x32_bf16(qa[s], kb, cs[nblk], 0, 0, 0);
      }
    }
    if (kt * 64 + 64 > Nk) {
#pragma unroll
      for (int nblk = 0; nblk < 4; ++nblk) {
        bool valid = (kt * 64 + nblk * 16 + col) < Nk;
#pragma unroll
        for (int r = 0; r < 4; ++r)
          cs[nblk][r] = valid ? cs[nblk][r] : -1e30f;
      }
    }
#pragma unroll
    for (int r = 0; r < 4; ++r) {
      int row = quad * 4 + r;
#pragma unroll
      for (int nblk = 0; nblk < 4; ++nblk) {
        float p = exp2f(fmaf(cs[nblk][r], scale, -M0));
        l_i[r] += p;
        int kin = (nblk & 1) * 16 + col;
        sPw[(nblk >> 1) * 512 + row * 32 + (kin ^ (quad << 3))] = f2b(p);
      }
    }
#pragma unroll
    for (int s = 0; s < 2; ++s) {
      bf16x8 pa = *(const bf16x8*)&sPw[s * 512 + col * 32 + ((quad ^ ((col >> 2) & 3)) << 3)];
#pragma unroll
      for (int nblk = 0; nblk < 4; ++nblk) {
        bf16x8 vb = *(const bf16x8*)&sV[bb][s * 2048 + (nblk * 16 + col) * 32 + quad * 8];
        oacc[nblk] = __builtin_amdgcn_mfma_f32_16x16x32_bf16(pa, vb, oacc[nblk], 0, 0, 0);
      }
    }
    if (kt + 1 < t1) __syncthreads();
    bb ^= 1;
  }
#undef STAGE_KV

#pragma unroll
  for (int r = 0; r < 4; ++r) {
    float ps = l_i[r];
#pragma unroll
    for (int o = 1; o < 16; o <<= 1) ps += __shfl_xor(ps, o);
    int qglob = b * N_DIM + q0 + w * 16 + quad * 4 + r;
    if (Opart) {
      if (col == 0) lbuf[(size_t)kc * (B_DIM * N_DIM * 12) + (size_t)qglob * 12 + h] = ps;
      float* op = Opart + (size_t)kc * MNX + (size_t)qglob * C_DIM + h * 64;
#pragma unroll
      for (int nblk = 0; nblk < 4; ++nblk)
        op[nblk * 16 + col] = oacc[nblk][r];
    } else {
      float inv = 1.f / ps;
#pragma unroll
      for (int nblk = 0; nblk < 4; ++nblk)
        O[(size_t)qglob * C_DIM + h * 64 + nblk * 16 + col] = f2b(oacc[nblk][r] * inv);
    }
  }
}

// ---------------- merge key-split attention partials ----------------------
__global__ __launch_bounds__(256)
void attn_merge(const float* __restrict__ Opart, const float* __restrict__ lbuf,
                ushort_t* __restrict__ Ob, int nchunk) {
  int idx = (blockIdx.x * 256 + threadIdx.x) * 4;
  if (idx >= MNX) return;
  int row = idx / C_DIM, c = idx % C_DIM;
  int h = c >> 6;
  float l = 0.f;
  float v[4] = {0.f, 0.f, 0.f, 0.f};
  for (int kc = 0; kc < nchunk; ++kc) {
    l += lbuf[(size_t)kc * (B_DIM * N_DIM * 12) + (size_t)row * 12 + h];
    float4 p = *(const float4*)&Opart[(size_t)kc * MNX + idx];
    v[0] += p.x; v[1] += p.y; v[2] += p.z; v[3] += p.w;
  }
  float inv = 1.f / l;
  ushort4 o;
  o.x = f2b(v[0] * inv); o.y = f2b(v[1] * inv);
  o.z = f2b(v[2] * inv); o.w = f2b(v[3] * inv);
  *(ushort4*)&Ob[idx] = o;
}

// ---------------- text gather ----------------------------------------------
__global__ __launch_bounds__(256)
void gather_text_kernel(const float* __restrict__ enc, ushort_t* __restrict__ out) {
  int r = blockIdx.x;
  int bb = r / TEXT_LEN, j = r % TEXT_LEN;
  const float* src = enc + ((size_t)bb * L_DIM + j) * C_DIM;
  ushort_t* dst = out + (size_t)r * C_DIM;
#pragma unroll
  for (int l = 0; l < 3; ++l) {
    int c = threadIdx.x + l * 256;
    dst[c] = f2b(src[c]);
  }
}

// ---------------------------------------------------------------------------
extern "C" void kernel_launch(void* const* d_in, const int* in_sizes, int n_in,
                              void* d_out, int out_size, void* d_ws, size_t ws_size,
                              hipStream_t stream) {
  const float* x        = (const float*)d_in[0];
  const float* enc      = (const float*)d_in[1];
  const float* ln1_g    = (const float*)d_in[2];
  const float* ln1_b    = (const float*)d_in[3];
  const float* ln2_g    = (const float*)d_in[4];
  const float* ln2_b    = (const float*)d_in[5];
  const float* sa_wq    = (const float*)d_in[6];
  const float* sa_wk    = (const float*)d_in[7];
  const float* sa_wv    = (const float*)d_in[8];
  const float* sa_wo    = (const float*)d_in[9];
  const float* sa_wo_b  = (const float*)d_in[10];
  const float* ff_ln_g  = (const float*)d_in[11];
  const float* ff_ln_b  = (const float*)d_in[12];
  const float* ff_w1    = (const float*)d_in[13];
  const float* ff_w2    = (const float*)d_in[14];
  const float* a_attn   = (const float*)d_in[15];
  const float* a_dense  = (const float*)d_in[16];
  const float* ca_wq    = (const float*)d_in[17];
  const float* ca_wk    = (const float*)d_in[18];
  const float* ca_wv    = (const float*)d_in[19];
  const float* ca_wo    = (const float*)d_in[20];
  const float* ca_wo_b  = (const float*)d_in[21];

  char* ws = (char*)d_ws;
  float*    x1     = (float*)(ws + WX1);
  float*    x2     = (float*)(ws + WX2);
  ushort_t* qkv_b  = (ushort_t*)(ws + WQKV);
  ushort_t* q2b    = (ushort_t*)(ws + WQKV);
  ushort_t* kv2b   = (ushort_t*)(ws + WQKV + 3145728u);
  ushort_t* comb_b = (ushort_t*)(ws + WBB1);
  float*    opart  = (float*)(ws + WOPART);
  float*    lbuf   = (float*)(ws + WLBUF);
  ushort_t* attn_b = (ushort_t*)(ws + WATTN);
  ushort_t* g_b    = (ushort_t*)(ws + WG);
  ushort_t* hh     = (ushort_t*)(ws + WS1);
  ushort_t* x2b    = (ushort_t*)(ws + WS1);
  ushort_t* text_b = (ushort_t*)(ws + WTEXT);
  ushort_t* attn2b = (ushort_t*)(ws + WATT2);
  ushort_t* wqkv_t = (ushort_t*)(ws + WWQKV);
  ushort_t* wo_t   = (ushort_t*)(ws + WWO);
  ushort_t* w1_t   = (ushort_t*)(ws + WW1);
  ushort_t* w2_t   = (ushort_t*)(ws + WW2);
  ushort_t* cawq_t = (ushort_t*)(ws + WCAWQ);
  ushort_t* cakv_t = (ushort_t*)(ws + WCAKV);
  ushort_t* cawo_t = (ushort_t*)(ws + WCAWO);
  ushort_t* vt1    = (ushort_t*)(ws + WVT1);
  ushort_t* vt2    = (ushort_t*)(ws + WVT2);
  float* out = (float*)d_out;

  const int Mc = B_DIM * NC_DIM;   // 2080
  const int Mx = B_DIM * N_DIM;    // 2048
  const int Mt = B_DIM * TEXT_LEN; // 154

  // ---- batched weight transposes (ff_w1 interleaved) ----
  WtDesc wd;
  const float* srcs[10] = {sa_wq, sa_wk, sa_wv, sa_wo, ca_wq, ca_wk, ca_wv, ca_wo, ff_w1, ff_w2};
  ushort_t* dsts[10] = {wqkv_t, wqkv_t + 589824, wqkv_t + 2 * 589824, wo_t,
                        cawq_t, cakv_t, cakv_t + 589824, cawo_t, w1_t, w2_t};
  int Ks[10] = {768, 768, 768, 768, 768, 768, 768, 768, 768, 3072};
  int Ns[10] = {768, 768, 768, 768, 768, 768, 768, 768, 6144, 768};
  int total = 0;
  for (int j = 0; j < 10; ++j) {
    wd.src[j] = srcs[j]; wd.dst[j] = dsts[j];
    wd.K[j] = Ks[j]; wd.N[j] = Ns[j];
    wd.tilesX[j] = Ns[j] / 64;
    wd.ileave[j] = (j == 8) ? 1 : 0;
    wd.start[j] = total;
    total += (Ns[j] / 64) * (Ks[j] / 64);
  }
  wd.start[10] = total;   // 2880

  wtrans_batched<<<total, 256, 0, stream>>>(wd);
  ln_concat_kernel<<<Mc, 256, 0, stream>>>(x, enc, ln1_g, ln1_b, comb_b);
  // qkv (128-tile): [2080,2304]
  gemm_bf16<<<dim3(18, 17), 256, 0, stream>>>(
      comb_b, wqkv_t, nullptr, qkv_b, nullptr, Mc, 2304, 768,
      nullptr, nullptr, nullptr);
  vtrans_kernel<<<dim3(17, 12, B_DIM), 256, 0, stream>>>(
      qkv_b + 1536, vt1, NC_DIM, 2304, NC_DIM, 1088);
  // self-attn: 4-way key split -> fp32 partials + l, then merge
  attn_mfma<<<dim3(N_DIM / 64, 12, B_DIM * 4), 256, 0, stream>>>(
      qkv_b + 0, qkv_b + 768, vt1, nullptr, opart, lbuf,
      NC_DIM, NC_DIM, NC_DIM, 1088, 2304, 2304, 4);
  attn_merge<<<MNX / 1024, 256, 0, stream>>>(opart, lbuf, attn_b, 4);
  // wo (64-tile, 384 blocks): x1 = x + tanh(a_attn)*(attn@wo + b)
  gemm64<<<dim3(12, 32), 256, 0, stream>>>(
      attn_b, wo_t, x1, nullptr, Mx, 768, 768, sa_wo_b, x, a_attn);
  ln_double_kernel<<<Mx, 256, 0, stream>>>(x1, ln2_g, ln2_b, ff_ln_g, ff_ln_b, hh);
  // ff1 + fused GEGLU (128-tile, interleaved w1) -> g_b [2048][3072]
  gemm_bf16<<<dim3(48, 16), 256, 0, stream>>>(
      hh, w1_t, nullptr, nullptr, g_b, Mx, 6144, 768,
      nullptr, nullptr, nullptr);
  // ff2 (64-tile, K=3072): x2 = x1 + tanh(a_dense)*(g@w2); x2b bf16
  gemm64<<<dim3(12, 32), 256, 0, stream>>>(
      g_b, w2_t, x2, x2b, Mx, 768, 3072, nullptr, x1, a_dense);
  gather_text_kernel<<<Mt, 256, 0, stream>>>(enc, text_b);
  // q2 (64-tile)
  gemm64<<<dim3(12, 32), 256, 0, stream>>>(
      x2b, cawq_t, nullptr, q2b, Mx, 768, 768, nullptr, nullptr, nullptr);
  // kv (128-tile, M=154)
  gemm_bf16<<<dim3(12, 2), 256, 0, stream>>>(
      text_b, cakv_t, nullptr, kv2b, nullptr, Mt, 1536, 768,
      nullptr, nullptr, nullptr);
  vtrans_kernel<<<dim3(2, 12, B_DIM), 256, 0, stream>>>(
      kv2b + 768, vt2, TEXT_LEN, 1536, TEXT_LEN, 128);
  // cross-attn: single chunk, in-kernel normalize
  attn_mfma<<<dim3(N_DIM / 64, 12, B_DIM), 256, 0, stream>>>(
      q2b, kv2b + 0, vt2, attn2b, nullptr, nullptr,
      N_DIM, TEXT_LEN, TEXT_LEN, 128, 768, 1536, 1);
  // final (64-tile): out = x2 + attn2@cawo + b
  gemm64<<<dim3(12, 32), 256, 0, stream>>>(
      attn2b, cawo_t, out, nullptr, Mx, 768, 768, ca_wo_b, x2, nullptr);
}

// Round 10
// 325.302 us; speedup vs baseline: 1.1643x; 1.1643x over previous
//
#include <hip/hip_runtime.h>
#include <hip/hip_bf16.h>
#include <math.h>

// ---------------------------------------------------------------------------
// FaceAttnProcessor forward. R9: gemm64 rebuilt with BK=64 (two 32-k
// sub-blocks, 8 MFMA/wave/iter) + split-K on top (ff2 z=4 -> 12 iters,
// wo/q2/fin z=2 -> 6 iters) to crush serial-iteration latency; qkv/kv on
// gemm64 for block count. ff1 keeps 128-tile + fused GEGLU. Attention =
// key-split static-max MFMA flash. B=2, N=1024, C=768, H=12, INNER=3072.
// ---------------------------------------------------------------------------

#define C_DIM 768
#define B_DIM 2
#define N_DIM 1024
#define NC_DIM 1040
#define L_DIM 93
#define TEXT_LEN 77
#define INNER 3072
#define MNX 1572864   // 2048*768

typedef unsigned short ushort_t;
typedef __bf16 bf16x8 __attribute__((ext_vector_type(8)));
typedef float f32x4 __attribute__((ext_vector_type(4)));

__device__ __forceinline__ ushort_t f2b(float f) {
  __hip_bfloat16 h = __float2bfloat16(f);
  return *(ushort_t*)&h;
}
__device__ __forceinline__ float b2f(ushort_t u) {
  __hip_bfloat16 h = *(__hip_bfloat16*)&u;
  return __bfloat162float(h);
}

__device__ __forceinline__ void g2lds16(const void* g, void* l) {
  __builtin_amdgcn_global_load_lds(
      (const __attribute__((address_space(1))) unsigned int*)g,
      (__attribute__((address_space(3))) unsigned int*)l, 16, 0, 0);
}

// ---------------- workspace map (byte offsets) ----------------------------
#define WX1    0u           // fp32 x1 (2048*768)
#define WX2    6291456u     // fp32 x2
#define WQKV   12582912u    // u16 qkv_b [2080][2304]; later q2b/kv2b
#define WBB1   22167552u    // comb_b / opart[4] / split-K partial slabs
#define WG     47333376u    // lbuf + attn_b (phase A) / g_b (phase C)
#define WS1    59916288u    // u16 hh / x2b [2048][768]
#define WTEXT  63062016u    // u16 text_b [154][768]
#define WATT2  63298560u    // u16 attn2b [2048][768]
#define WWQKV  66444288u    // u16 wqkv_t [2304][768]
#define WWO    69983232u    // u16 wo_t   [768][768]
#define WW1    71162880u    // u16 w1_t   [6144][768] (interleaved a/gate rows)
#define WW2    80600064u    // u16 w2_t   [768][3072]
#define WCAWQ  85318656u    // u16 cawq_t [768][768]
#define WCAKV  86498304u    // u16 cakv_t [1536][768]
#define WCAWO  88857600u    // u16 cawo_t [768][768]
#define WVT1   90037248u    // u16 Vt self  [2][12][64][1088]
#define WVT2   93379584u    // u16 Vt cross [2][12][64][128]
#define WOPART WBB1                 // fp32 opart[4][2048][768] = 25,165,824
#define WLBUF  WG                   // fp32 lbuf[4][2048][12]
#define WATTN  (WG + 524288u)       // u16 attn_b (dead before g_b written)
#define WPART  WBB1                 // fp32 split-K partials (<=4 slabs)
// end: 93,772,800 B

// ---------------- block reduction (256 threads = 4 waves) -----------------
__device__ __forceinline__ float block_sum(float v, float* sh) {
#pragma unroll
  for (int o = 32; o > 0; o >>= 1) v += __shfl_down(v, o);
  int lane = threadIdx.x & 63, w = threadIdx.x >> 6;
  if (lane == 0) sh[w] = v;
  __syncthreads();
  float r = sh[0] + sh[1] + sh[2] + sh[3];
  __syncthreads();
  return r;
}

// ---------------- batched weight cast+transpose ---------------------------
struct WtDesc {
  const float* src[10];
  ushort_t*    dst[10];
  int K[10];
  int N[10];
  int tilesX[10];
  int ileave[10];
  int start[11];
};

__global__ __launch_bounds__(256)
void wtrans_batched(WtDesc d) {
  __shared__ float tile[64][65];
  int bid = blockIdx.x;
  int j = 0;
  while (j < 9 && bid >= d.start[j + 1]) ++j;
  int ti = bid - d.start[j];
  int K = d.K[j], N = d.N[j];
  int n0 = (ti % d.tilesX[j]) * 64, k0 = (ti / d.tilesX[j]) * 64;
  const float* in = d.src[j];
  ushort_t* out = d.dst[j];
  int il = d.ileave[j];
  int t = threadIdx.x;
#pragma unroll
  for (int p = 0; p < 16; ++p) {
    int idx = t + p * 256;
    int r = idx >> 6, c = idx & 63;
    tile[r][c] = in[(size_t)(k0 + r) * N + n0 + c];
  }
  __syncthreads();
#pragma unroll
  for (int p = 0; p < 16; ++p) {
    int idx = t + p * 256;
    int r = idx >> 6, c = idx & 63;
    int nrow = n0 + r;
    int dstrow = il ? ((nrow < INNER) ? (nrow * 2) : ((nrow - INNER) * 2 + 1)) : nrow;
    out[(size_t)dstrow * K + k0 + c] = f2b(tile[c][r]);
  }
}

// ---------------- LN(x) and LN(face) -> comb (bf16) -----------------------
__global__ __launch_bounds__(256)
void ln_concat_kernel(const float* __restrict__ x, const float* __restrict__ enc,
                      const float* __restrict__ g, const float* __restrict__ b,
                      ushort_t* __restrict__ comb) {
  __shared__ float sh[4];
  int r = blockIdx.x;
  int bb = r / NC_DIM, i = r % NC_DIM;
  const float* src = (i < N_DIM)
      ? (x   + ((size_t)bb * N_DIM + i) * C_DIM)
      : (enc + ((size_t)bb * L_DIM + TEXT_LEN + (i - N_DIM)) * C_DIM);
  float v[3];
#pragma unroll
  for (int j = 0; j < 3; ++j) v[j] = src[threadIdx.x + j * 256];
  float mean = block_sum(v[0] + v[1] + v[2], sh) * (1.f / C_DIM);
  float sq = 0.f;
#pragma unroll
  for (int j = 0; j < 3; ++j) { float d = v[j] - mean; sq += d * d; }
  float rstd = rsqrtf(block_sum(sq, sh) * (1.f / C_DIM) + 1e-5f);
  ushort_t* dst = comb + (size_t)r * C_DIM;
#pragma unroll
  for (int j = 0; j < 3; ++j) {
    int c = threadIdx.x + j * 256;
    dst[c] = f2b((v[j] - mean) * rstd * g[c] + b[c]);
  }
}

// ---------------- bf16 MFMA GEMM, 128x128 tile (ff1 + GEGLU) ---------------
__global__ __launch_bounds__(256)
void gemm_bf16(const ushort_t* __restrict__ A, const ushort_t* __restrict__ Bt,
               ushort_t* __restrict__ Ob, ushort_t* __restrict__ Og,
               int M, int N, int K) {
  __shared__ ushort_t sA[2][128 * 32];
  __shared__ ushort_t sB[2][128 * 32];
  int t = threadIdx.x;
  int w = t >> 6, ln = t & 63;
  int m0 = blockIdx.y * 128, n0 = blockIdx.x * 128;
  int wm = (w >> 1) * 64, wn = (w & 1) * 64;
  int lr = ln & 15, lq = ln >> 4;
  int seg_r = ln >> 2, seg_c = (ln & 3) * 8;

  f32x4 acc[4][4];
#pragma unroll
  for (int mi = 0; mi < 4; ++mi)
#pragma unroll
    for (int ni = 0; ni < 4; ++ni) acc[mi][ni] = (f32x4){0.f, 0.f, 0.f, 0.f};

#define STAGE(k0_, buf_)                                                     \
  do {                                                                       \
    _Pragma("unroll") for (int l = 0; l < 2; ++l) {                          \
      int s = w * 2 + l;                                                     \
      int arow = m0 + s * 16 + seg_r;                                        \
      arow = arow < M ? arow : M - 1;                                        \
      g2lds16(A + (size_t)arow * K + (k0_) + seg_c, &sA[buf_][s * 512]);     \
      int nrow = n0 + s * 16 + seg_r;                                        \
      g2lds16(Bt + (size_t)nrow * K + (k0_) + seg_c, &sB[buf_][s * 512]);    \
    }                                                                        \
  } while (0)

  STAGE(0, 0);
  __syncthreads();
  int cur = 0;
  for (int k0 = 0; k0 < K; k0 += 32) {
    if (k0 + 32 < K) STAGE(k0 + 32, cur ^ 1);
    bf16x8 af[4], bfr[4];
#pragma unroll
    for (int mi = 0; mi < 4; ++mi)
      af[mi] = *(const bf16x8*)&sA[cur][(wm + mi * 16 + lr) * 32 + lq * 8];
#pragma unroll
    for (int ni = 0; ni < 4; ++ni)
      bfr[ni] = *(const bf16x8*)&sB[cur][(wn + ni * 16 + lr) * 32 + lq * 8];
#pragma unroll
    for (int mi = 0; mi < 4; ++mi)
#pragma unroll
      for (int ni = 0; ni < 4; ++ni)
        acc[mi][ni] = __builtin_amdgcn_mfma_f32_16x16x32_bf16(
            af[mi], bfr[ni], acc[mi][ni], 0, 0, 0);
    __syncthreads();
    cur ^= 1;
  }
#undef STAGE

  if (Og) {
#pragma unroll
    for (int mi = 0; mi < 4; ++mi)
#pragma unroll
      for (int ni = 0; ni < 4; ++ni) {
        int col = n0 + wn + ni * 16 + lr;
#pragma unroll
        for (int r = 0; r < 4; ++r) {
          float val = acc[mi][ni][r];
          float other = __shfl_xor(val, 1);
          if (!(lr & 1)) {
            float a = val, gate = other;
            float ge = 0.5f * gate * (1.f + erff(gate * 0.70710678118654752f));
            int row = m0 + wm + mi * 16 + lq * 4 + r;
            Og[(size_t)row * INNER + (col >> 1)] = f2b(a * ge);
          }
        }
      }
  } else {
#pragma unroll
    for (int mi = 0; mi < 4; ++mi)
#pragma unroll
      for (int ni = 0; ni < 4; ++ni) {
        int col = n0 + wn + ni * 16 + lr;
#pragma unroll
        for (int r = 0; r < 4; ++r) {
          int row = m0 + wm + mi * 16 + lq * 4 + r;
          if (row < M) Ob[(size_t)row * N + col] = f2b(acc[mi][ni][r]);
        }
      }
  }
}

// ---------------- bf16 MFMA GEMM, 64x64 tile, BK=64, optional split-K ------
// 4 waves, each 32x32 subtile (2x2 MFMA), 8 MFMA/wave/iter. LDS = two
// m97-style [64][32] sub-blocks per buffer. grid.z = K/Ksplit splits;
// Part!=null: fp32 partial slabs (epilogue kernels reduce); else fused
// bias/res/alpha epilogue.
__global__ __launch_bounds__(256)
void gemm64(const ushort_t* __restrict__ A, const ushort_t* __restrict__ Bt,
            float* __restrict__ Out, ushort_t* __restrict__ Ob,
            float* __restrict__ Part,
            int M, int N, int K, int Ksplit,
            const float* __restrict__ bias, const float* __restrict__ res,
            const float* __restrict__ alphaPtr) {
  __shared__ ushort_t sA[2][4096];   // [buf][s*2048 + row*32 + k]
  __shared__ ushort_t sB[2][4096];
  int t = threadIdx.x;
  int w = t >> 6, ln = t & 63;
  int m0 = blockIdx.y * 64, n0 = blockIdx.x * 64;
  int wm = (w >> 1) * 32, wn = (w & 1) * 32;
  int lr = ln & 15, lq = ln >> 4;
  int srow = (w & 1) * 32 + (ln >> 2);        // staging row (+ i*16)
  int skoff = (w >> 1) * 32 + (ln & 3) * 8;   // staging k offset
  int kbeg = blockIdx.z * Ksplit;
  int kend = kbeg + Ksplit; if (kend > K) kend = K;

  f32x4 acc[2][2];
#pragma unroll
  for (int mi = 0; mi < 2; ++mi)
#pragma unroll
    for (int ni = 0; ni < 2; ++ni) acc[mi][ni] = (f32x4){0.f, 0.f, 0.f, 0.f};

#define STG64(k0_, buf_)                                                      \
  do {                                                                        \
    _Pragma("unroll") for (int i = 0; i < 2; ++i) {                           \
      int ar = m0 + srow + i * 16; ar = ar < M ? ar : M - 1;                  \
      g2lds16(A + (size_t)ar * K + (k0_) + skoff,                             \
              (char*)sA + (buf_) * 8192 + w * 2048 + i * 1024);               \
      int nr = n0 + srow + i * 16;                                            \
      g2lds16(Bt + (size_t)nr * K + (k0_) + skoff,                            \
              (char*)sB + (buf_) * 8192 + w * 2048 + i * 1024);               \
    }                                                                         \
  } while (0)

  STG64(kbeg, 0);
  __syncthreads();
  int cur = 0;
  for (int k0 = kbeg; k0 < kend; k0 += 64) {
    if (k0 + 64 < kend) STG64(k0 + 64, cur ^ 1);
#pragma unroll
    for (int s = 0; s < 2; ++s) {
      bf16x8 a0 = *(const bf16x8*)&sA[cur][s * 2048 + (wm + lr) * 32 + lq * 8];
      bf16x8 a1 = *(const bf16x8*)&sA[cur][s * 2048 + (wm + 16 + lr) * 32 + lq * 8];
      bf16x8 b0 = *(const bf16x8*)&sB[cur][s * 2048 + (wn + lr) * 32 + lq * 8];
      bf16x8 b1 = *(const bf16x8*)&sB[cur][s * 2048 + (wn + 16 + lr) * 32 + lq * 8];
      acc[0][0] = __builtin_amdgcn_mfma_f32_16x16x32_bf16(a0, b0, acc[0][0], 0, 0, 0);
      acc[0][1] = __builtin_amdgcn_mfma_f32_16x16x32_bf16(a0, b1, acc[0][1], 0, 0, 0);
      acc[1][0] = __builtin_amdgcn_mfma_f32_16x16x32_bf16(a1, b0, acc[1][0], 0, 0, 0);
      acc[1][1] = __builtin_amdgcn_mfma_f32_16x16x32_bf16(a1, b1, acc[1][1], 0, 0, 0);
    }
    __syncthreads();
    cur ^= 1;
  }
#undef STG64

  if (Part) {
    float* P = Part + (size_t)blockIdx.z * M * N;
#pragma unroll
    for (int mi = 0; mi < 2; ++mi)
#pragma unroll
      for (int ni = 0; ni < 2; ++ni) {
        int col = n0 + wn + ni * 16 + lr;
#pragma unroll
        for (int r = 0; r < 4; ++r) {
          int row = m0 + wm + mi * 16 + lq * 4 + r;
          if (row < M) P[(size_t)row * N + col] = acc[mi][ni][r];
        }
      }
  } else {
    float f = alphaPtr ? tanhf(alphaPtr[0]) : 1.0f;
#pragma unroll
    for (int mi = 0; mi < 2; ++mi)
#pragma unroll
      for (int ni = 0; ni < 2; ++ni) {
        int col = n0 + wn + ni * 16 + lr;
        float bv = bias ? bias[col] : 0.f;
#pragma unroll
        for (int r = 0; r < 4; ++r) {
          int row = m0 + wm + mi * 16 + lq * 4 + r;
          if (row < M) {
            float val = acc[mi][ni][r] + bv;
            if (res) val = res[(size_t)row * N + col] + f * val;
            if (Out) Out[(size_t)row * N + col] = val;
            if (Ob)  Ob[(size_t)row * N + col] = f2b(val);
          }
        }
      }
  }
}

// ---------------- split-K reduce epilogue ----------------------------------
__global__ __launch_bounds__(256)
void splitk_epi(const float* __restrict__ Part, int nz, float* __restrict__ Out,
                ushort_t* __restrict__ Ob, int MN, int N,
                const float* __restrict__ bias, const float* __restrict__ res,
                const float* __restrict__ alphaPtr) {
  int idx = (blockIdx.x * 256 + threadIdx.x) * 4;
  if (idx >= MN) return;
  float f = alphaPtr ? tanhf(alphaPtr[0]) : 1.0f;
  float v[4] = {0.f, 0.f, 0.f, 0.f};
  for (int z = 0; z < nz; ++z) {
    float4 a = *(const float4*)&Part[(size_t)z * MN + idx];
    v[0] += a.x; v[1] += a.y; v[2] += a.z; v[3] += a.w;
  }
  if (bias) {
    int col = idx % N;
    float4 bb = *(const float4*)&bias[col];
    v[0] += bb.x; v[1] += bb.y; v[2] += bb.z; v[3] += bb.w;
  }
  if (res) {
    float4 rr = *(const float4*)&res[idx];
    v[0] = rr.x + f * v[0]; v[1] = rr.y + f * v[1];
    v[2] = rr.z + f * v[2]; v[3] = rr.w + f * v[3];
  }
  if (Out) *(float4*)&Out[idx] = make_float4(v[0], v[1], v[2], v[3]);
  if (Ob) {
    ushort4 o;
    o.x = f2b(v[0]); o.y = f2b(v[1]); o.z = f2b(v[2]); o.w = f2b(v[3]);
    *(ushort4*)&Ob[idx] = o;
  }
}

// ---------------- fused wo-epilogue + double layernorm --------------------
__global__ __launch_bounds__(256)
void woepi_ln_kernel(const float* __restrict__ Part, int nz,
                     const float* __restrict__ bias, const float* __restrict__ xres,
                     const float* __restrict__ alphaPtr, float* __restrict__ x1,
                     const float* __restrict__ g1, const float* __restrict__ b1,
                     const float* __restrict__ g2, const float* __restrict__ b2,
                     ushort_t* __restrict__ hh) {
  __shared__ float sh[4];
  int row = blockIdx.x;
  float f = tanhf(alphaPtr[0]);
  float v[3];
#pragma unroll
  for (int j = 0; j < 3; ++j) {
    int c = threadIdx.x + j * 256;
    float s = 0.f;
    for (int z = 0; z < nz; ++z) s += Part[(size_t)z * MNX + (size_t)row * C_DIM + c];
    s += bias[c];
    float xv = xres[(size_t)row * C_DIM + c] + f * s;
    x1[(size_t)row * C_DIM + c] = xv;
    v[j] = xv;
  }
  float mean = block_sum(v[0] + v[1] + v[2], sh) * (1.f / C_DIM);
  float sq = 0.f;
#pragma unroll
  for (int j = 0; j < 3; ++j) { float d = v[j] - mean; sq += d * d; }
  float rstd = rsqrtf(block_sum(sq, sh) * (1.f / C_DIM) + 1e-5f);
  float y[3];
#pragma unroll
  for (int j = 0; j < 3; ++j) {
    int c = threadIdx.x + j * 256;
    y[j] = (v[j] - mean) * rstd * g1[c] + b1[c];
  }
  float mean2 = block_sum(y[0] + y[1] + y[2], sh) * (1.f / C_DIM);
  sq = 0.f;
#pragma unroll
  for (int j = 0; j < 3; ++j) { float d = y[j] - mean2; sq += d * d; }
  float rstd2 = rsqrtf(block_sum(sq, sh) * (1.f / C_DIM) + 1e-5f);
#pragma unroll
  for (int j = 0; j < 3; ++j) {
    int c = threadIdx.x + j * 256;
    hh[(size_t)row * C_DIM + c] = f2b((y[j] - mean2) * rstd2 * g2[c] + b2[c]);
  }
}

// ---------------- V transpose: strided bf16 [key][64] -> Vt [dv][Nkp] -----
__global__ __launch_bounds__(256)
void vtrans_kernel(const ushort_t* __restrict__ V, ushort_t* __restrict__ Vt,
                   int rows_per_b, int stride, int Nk, int Nkp) {
  __shared__ ushort_t tile[64][68];
  int k0 = blockIdx.x * 64;
  int h = blockIdx.y, b = blockIdx.z;
  int t = threadIdx.x;
#pragma unroll
  for (int p = 0; p < 4; ++p) {
    int r = p * 16 + (t >> 4), c = (t & 15) * 4;
    int key = k0 + r;
    ushort4 u = make_ushort4(0, 0, 0, 0);
    if (key < Nk)
      u = *(const ushort4*)&V[((size_t)(b * rows_per_b + key)) * stride + h * 64 + c];
    *(ushort4*)&tile[r][c] = u;
  }
  __syncthreads();
  size_t base = ((size_t)(b * 12 + h)) * 64 * Nkp;
#pragma unroll
  for (int p = 0; p < 4; ++p) {
    int dv = p * 16 + (t >> 4), kc = (t & 15) * 4;
    ushort4 u;
    u.x = tile[kc + 0][dv]; u.y = tile[kc + 1][dv];
    u.z = tile[kc + 2][dv]; u.w = tile[kc + 3][dv];
    *(ushort4*)&Vt[base + (size_t)dv * Nkp + k0 + kc] = u;
  }
}

// ---------------- MFMA flash attention (key-split + static-max) -----------
__global__ __launch_bounds__(256)
void attn_mfma(const ushort_t* __restrict__ Q, const ushort_t* __restrict__ K,
               const ushort_t* __restrict__ Vt, ushort_t* __restrict__ O,
               float* __restrict__ Opart, float* __restrict__ lbuf,
               int q_rows_per_b, int kv_rows_per_b, int Nk, int Nkp,
               int qstride, int kstride, int nchunk) {
  __shared__ ushort_t sQ[4096];
  __shared__ ushort_t sK[2][4096];
  __shared__ ushort_t sV[2][4096];
  __shared__ ushort_t sP[4][1024];
  const float scale = 0.18033688011112042f;   // 1/8 * log2(e)
  const float M0 = 16.0f;
  int t = threadIdx.x;
  int w = t >> 6, ln = t & 63;
  int col = ln & 15, quad = ln >> 4;
  int z = blockIdx.z;
  int b = z / nchunk, kc = z % nchunk;
  int h = blockIdx.y, q0 = blockIdx.x * 64;
  size_t vt_base = ((size_t)(b * 12 + h)) * 64 * Nkp;
  int ntiles = Nkp >> 6;
  int t0 = (kc * ntiles) / nchunk;
  int t1 = ((kc + 1) * ntiles) / nchunk;

#define STAGE_KV(kt_, bb_)                                                    \
  do {                                                                        \
    _Pragma("unroll") for (int s = 0; s < 2; ++s) {                           \
      int key = (kt_) * 64 + w * 16 + (ln >> 2);                              \
      g2lds16(K + (size_t)(b * kv_rows_per_b + key) * kstride                 \
                + h * 64 + s * 32 + (ln & 3) * 8,                             \
              (char*)sK[bb_] + s * 4096 + w * 1024);                          \
      int dv = w * 16 + (ln >> 2);                                            \
      g2lds16(Vt + vt_base + (size_t)dv * Nkp                                 \
                + (kt_) * 64 + s * 32 + (ln & 3) * 8,                         \
              (char*)sV[bb_] + s * 4096 + w * 1024);                          \
    }                                                                         \
  } while (0)

#pragma unroll
  for (int s = 0; s < 2; ++s) {
    int r = q0 + w * 16 + (ln >> 2);
    g2lds16(Q + (size_t)(b * q_rows_per_b + r) * qstride + h * 64 + s * 32 + (ln & 3) * 8,
            (char*)sQ + s * 4096 + w * 1024);
  }
  STAGE_KV(t0, 0);
  __syncthreads();
  bf16x8 qa[2];
#pragma unroll
  for (int s = 0; s < 2; ++s)
    qa[s] = *(const bf16x8*)&sQ[s * 2048 + (w * 16 + col) * 32 + quad * 8];

  f32x4 oacc[4];
#pragma unroll
  for (int i = 0; i < 4; ++i) oacc[i] = (f32x4){0.f, 0.f, 0.f, 0.f};
  float l_i[4] = {0.f, 0.f, 0.f, 0.f};

  ushort_t* sPw = sP[w];
  int bb = 0;

  for (int kt = t0; kt < t1; ++kt) {
    if (kt + 1 < t1) STAGE_KV(kt + 1, bb ^ 1);

    f32x4 cs[4];
#pragma unroll
    for (int nblk = 0; nblk < 4; ++nblk) {
      cs[nblk] = (f32x4){0.f, 0.f, 0.f, 0.f};
#pragma unroll
      for (int s = 0; s < 2; ++s) {
        bf16x8 kb = *(const bf16x8*)&sK[bb][s * 2048 + (nblk * 16 + col) * 32 + quad * 8];
        cs[nblk] = __builtin_amdgcn_mfma_f32_16x16x32_bf16(qa[s], kb, cs[nblk], 0, 0, 0);
      }
    }
    if (kt * 64 + 64 > Nk) {
#pragma unroll
      for (int nblk = 0; nblk < 4; ++nblk) {
        bool valid = (kt * 64 + nblk * 16 + col) < Nk;
#pragma unroll
        for (int r = 0; r < 4; ++r)
          cs[nblk][r] = valid ? cs[nblk][r] : -1e30f;
      }
    }
#pragma unroll
    for (int r = 0; r < 4; ++r) {
      int row = quad * 4 + r;
#pragma unroll
      for (int nblk = 0; nblk < 4; ++nblk) {
        float p = exp2f(fmaf(cs[nblk][r], scale, -M0));
        l_i[r] += p;
        int kin = (nblk & 1) * 16 + col;
        sPw[(nblk >> 1) * 512 + row * 32 + (kin ^ (quad << 3))] = f2b(p);
      }
    }
#pragma unroll
    for (int s = 0; s < 2; ++s) {
      bf16x8 pa = *(const bf16x8*)&sPw[s * 512 + col * 32 + ((quad ^ ((col >> 2) & 3)) << 3)];
#pragma unroll
      for (int nblk = 0; nblk < 4; ++nblk) {
        bf16x8 vb = *(const bf16x8*)&sV[bb][s * 2048 + (nblk * 16 + col) * 32 + quad * 8];
        oacc[nblk] = __builtin_amdgcn_mfma_f32_16x16x32_bf16(pa, vb, oacc[nblk], 0, 0, 0);
      }
    }
    if (kt + 1 < t1) __syncthreads();
    bb ^= 1;
  }
#undef STAGE_KV

#pragma unroll
  for (int r = 0; r < 4; ++r) {
    float ps = l_i[r];
#pragma unroll
    for (int o = 1; o < 16; o <<= 1) ps += __shfl_xor(ps, o);
    int qglob = b * N_DIM + q0 + w * 16 + quad * 4 + r;
    if (Opart) {
      if (col == 0) lbuf[(size_t)kc * (B_DIM * N_DIM * 12) + (size_t)qglob * 12 + h] = ps;
      float* op = Opart + (size_t)kc * MNX + (size_t)qglob * C_DIM + h * 64;
#pragma unroll
      for (int nblk = 0; nblk < 4; ++nblk)
        op[nblk * 16 + col] = oacc[nblk][r];
    } else {
      float inv = 1.f / ps;
#pragma unroll
      for (int nblk = 0; nblk < 4; ++nblk)
        O[(size_t)qglob * C_DIM + h * 64 + nblk * 16 + col] = f2b(oacc[nblk][r] * inv);
    }
  }
}

// ---------------- merge key-split attention partials ----------------------
__global__ __launch_bounds__(256)
void attn_merge(const float* __restrict__ Opart, const float* __restrict__ lbuf,
                ushort_t* __restrict__ Ob, int nchunk) {
  int idx = (blockIdx.x * 256 + threadIdx.x) * 4;
  if (idx >= MNX) return;
  int row = idx / C_DIM, c = idx % C_DIM;
  int h = c >> 6;
  float l = 0.f;
  float v[4] = {0.f, 0.f, 0.f, 0.f};
  for (int kc = 0; kc < nchunk; ++kc) {
    l += lbuf[(size_t)kc * (B_DIM * N_DIM * 12) + (size_t)row * 12 + h];
    float4 p = *(const float4*)&Opart[(size_t)kc * MNX + idx];
    v[0] += p.x; v[1] += p.y; v[2] += p.z; v[3] += p.w;
  }
  float inv = 1.f / l;
  ushort4 o;
  o.x = f2b(v[0] * inv); o.y = f2b(v[1] * inv);
  o.z = f2b(v[2] * inv); o.w = f2b(v[3] * inv);
  *(ushort4*)&Ob[idx] = o;
}

// ---------------- text gather ----------------------------------------------
__global__ __launch_bounds__(256)
void gather_text_kernel(const float* __restrict__ enc, ushort_t* __restrict__ out) {
  int r = blockIdx.x;
  int bb = r / TEXT_LEN, j = r % TEXT_LEN;
  const float* src = enc + ((size_t)bb * L_DIM + j) * C_DIM;
  ushort_t* dst = out + (size_t)r * C_DIM;
#pragma unroll
  for (int l = 0; l < 3; ++l) {
    int c = threadIdx.x + l * 256;
    dst[c] = f2b(src[c]);
  }
}

// ---------------------------------------------------------------------------
extern "C" void kernel_launch(void* const* d_in, const int* in_sizes, int n_in,
                              void* d_out, int out_size, void* d_ws, size_t ws_size,
                              hipStream_t stream) {
  const float* x        = (const float*)d_in[0];
  const float* enc      = (const float*)d_in[1];
  const float* ln1_g    = (const float*)d_in[2];
  const float* ln1_b    = (const float*)d_in[3];
  const float* ln2_g    = (const float*)d_in[4];
  const float* ln2_b    = (const float*)d_in[5];
  const float* sa_wq    = (const float*)d_in[6];
  const float* sa_wk    = (const float*)d_in[7];
  const float* sa_wv    = (const float*)d_in[8];
  const float* sa_wo    = (const float*)d_in[9];
  const float* sa_wo_b  = (const float*)d_in[10];
  const float* ff_ln_g  = (const float*)d_in[11];
  const float* ff_ln_b  = (const float*)d_in[12];
  const float* ff_w1    = (const float*)d_in[13];
  const float* ff_w2    = (const float*)d_in[14];
  const float* a_attn   = (const float*)d_in[15];
  const float* a_dense  = (const float*)d_in[16];
  const float* ca_wq    = (const float*)d_in[17];
  const float* ca_wk    = (const float*)d_in[18];
  const float* ca_wv    = (const float*)d_in[19];
  const float* ca_wo    = (const float*)d_in[20];
  const float* ca_wo_b  = (const float*)d_in[21];

  char* ws = (char*)d_ws;
  float*    x1     = (float*)(ws + WX1);
  float*    x2     = (float*)(ws + WX2);
  ushort_t* qkv_b  = (ushort_t*)(ws + WQKV);
  ushort_t* q2b    = (ushort_t*)(ws + WQKV);
  ushort_t* kv2b   = (ushort_t*)(ws + WQKV + 3145728u);
  ushort_t* comb_b = (ushort_t*)(ws + WBB1);
  float*    opart  = (float*)(ws + WOPART);
  float*    lbuf   = (float*)(ws + WLBUF);
  ushort_t* attn_b = (ushort_t*)(ws + WATTN);
  ushort_t* g_b    = (ushort_t*)(ws + WG);
  ushort_t* hh     = (ushort_t*)(ws + WS1);
  ushort_t* x2b    = (ushort_t*)(ws + WS1);
  ushort_t* text_b = (ushort_t*)(ws + WTEXT);
  ushort_t* attn2b = (ushort_t*)(ws + WATT2);
  ushort_t* wqkv_t = (ushort_t*)(ws + WWQKV);
  ushort_t* wo_t   = (ushort_t*)(ws + WWO);
  ushort_t* w1_t   = (ushort_t*)(ws + WW1);
  ushort_t* w2_t   = (ushort_t*)(ws + WW2);
  ushort_t* cawq_t = (ushort_t*)(ws + WCAWQ);
  ushort_t* cakv_t = (ushort_t*)(ws + WCAKV);
  ushort_t* cawo_t = (ushort_t*)(ws + WCAWO);
  ushort_t* vt1    = (ushort_t*)(ws + WVT1);
  ushort_t* vt2    = (ushort_t*)(ws + WVT2);
  float* part = (float*)(ws + WPART);
  float* out = (float*)d_out;

  const int Mc = B_DIM * NC_DIM;   // 2080
  const int Mx = B_DIM * N_DIM;    // 2048
  const int Mt = B_DIM * TEXT_LEN; // 154

  // ---- batched weight transposes (ff_w1 interleaved) ----
  WtDesc wd;
  const float* srcs[10] = {sa_wq, sa_wk, sa_wv, sa_wo, ca_wq, ca_wk, ca_wv, ca_wo, ff_w1, ff_w2};
  ushort_t* dsts[10] = {wqkv_t, wqkv_t + 589824, wqkv_t + 2 * 589824, wo_t,
                        cawq_t, cakv_t, cakv_t + 589824, cawo_t, w1_t, w2_t};
  int Ks[10] = {768, 768, 768, 768, 768, 768, 768, 768, 768, 3072};
  int Ns[10] = {768, 768, 768, 768, 768, 768, 768, 768, 6144, 768};
  int total = 0;
  for (int j = 0; j < 10; ++j) {
    wd.src[j] = srcs[j]; wd.dst[j] = dsts[j];
    wd.K[j] = Ks[j]; wd.N[j] = Ns[j];
    wd.tilesX[j] = Ns[j] / 64;
    wd.ileave[j] = (j == 8) ? 1 : 0;
    wd.start[j] = total;
    total += (Ns[j] / 64) * (Ks[j] / 64);
  }
  wd.start[10] = total;   // 2880

  wtrans_batched<<<total, 256, 0, stream>>>(wd);
  ln_concat_kernel<<<Mc, 256, 0, stream>>>(x, enc, ln1_g, ln1_b, comb_b);
  // qkv: gemm64, 36x33 = 1188 blocks, 12 iters
  gemm64<<<dim3(36, 33, 1), 256, 0, stream>>>(
      comb_b, wqkv_t, nullptr, qkv_b, nullptr, Mc, 2304, 768, 768,
      nullptr, nullptr, nullptr);
  vtrans_kernel<<<dim3(17, 12, B_DIM), 256, 0, stream>>>(
      qkv_b + 1536, vt1, NC_DIM, 2304, NC_DIM, 1088);
  // self-attn: 4-way key split -> fp32 partials + l, then merge
  attn_mfma<<<dim3(N_DIM / 64, 12, B_DIM * 4), 256, 0, stream>>>(
      qkv_b + 0, qkv_b + 768, vt1, nullptr, opart, lbuf,
      NC_DIM, NC_DIM, NC_DIM, 1088, 2304, 2304, 4);
  attn_merge<<<MNX / 1024, 256, 0, stream>>>(opart, lbuf, attn_b, 4);
  // wo: gemm64 split-K z=2 (6 iters, 768 blocks) -> woepi_ln
  gemm64<<<dim3(12, 32, 2), 256, 0, stream>>>(
      attn_b, wo_t, nullptr, nullptr, part, Mx, 768, 768, 384,
      nullptr, nullptr, nullptr);
  woepi_ln_kernel<<<Mx, 256, 0, stream>>>(
      part, 2, sa_wo_b, x, a_attn, x1, ln2_g, ln2_b, ff_ln_g, ff_ln_b, hh);
  // ff1 + fused GEGLU (128-tile, interleaved w1) -> g_b [2048][3072]
  gemm_bf16<<<dim3(48, 16), 256, 0, stream>>>(
      hh, w1_t, nullptr, g_b, Mx, 6144, 768);
  // ff2: gemm64 split-K z=4 (12 iters, 1536 blocks) -> splitk_epi
  gemm64<<<dim3(12, 32, 4), 256, 0, stream>>>(
      g_b, w2_t, nullptr, nullptr, part, Mx, 768, 3072, 768,
      nullptr, nullptr, nullptr);
  splitk_epi<<<MNX / 1024, 256, 0, stream>>>(
      part, 4, x2, x2b, MNX, 768, nullptr, x1, a_dense);
  gather_text_kernel<<<Mt, 256, 0, stream>>>(enc, text_b);
  // q2: gemm64 split-K z=2 -> splitk_epi (bf16 only)
  gemm64<<<dim3(12, 32, 2), 256, 0, stream>>>(
      x2b, cawq_t, nullptr, nullptr, part, Mx, 768, 768, 384,
      nullptr, nullptr, nullptr);
  splitk_epi<<<MNX / 1024, 256, 0, stream>>>(
      part, 2, nullptr, q2b, MNX, 768, nullptr, nullptr, nullptr);
  // kv: gemm64, 24x3 = 72 blocks
  gemm64<<<dim3(24, 3, 1), 256, 0, stream>>>(
      text_b, cakv_t, nullptr, kv2b, nullptr, Mt, 1536, 768, 768,
      nullptr, nullptr, nullptr);
  vtrans_kernel<<<dim3(2, 12, B_DIM), 256, 0, stream>>>(
      kv2b + 768, vt2, TEXT_LEN, 1536, TEXT_LEN, 128);
  // cross-attn: single chunk, in-kernel normalize
  attn_mfma<<<dim3(N_DIM / 64, 12, B_DIM), 256, 0, stream>>>(
      q2b, kv2b + 0, vt2, attn2b, nullptr, nullptr,
      N_DIM, TEXT_LEN, TEXT_LEN, 128, 768, 1536, 1);
  // final: gemm64 split-K z=2 -> splitk_epi (fp32 out + residual)
  gemm64<<<dim3(12, 32, 2), 256, 0, stream>>>(
      attn2b, cawo_t, nullptr, nullptr, part, Mx, 768, 768, 384,
      nullptr, nullptr, nullptr);
  splitk_epi<<<MNX / 1024, 256, 0, stream>>>(
      part, 2, out, nullptr, MNX, 768, ca_wo_b, x2, nullptr);
}